// Round 5
// baseline (3162.270 us; speedup 1.0000x reference)
//
#include <hip/hip_runtime.h>
#include <hip/hip_bf16.h>

// ---------------------------------------------------------------------------
// RNNModel (MDN-RNN): embed+concat -> x_pre -> 511-step LSTM -> out GEMM ->
// logsumexp heads.
//   lstm_k: persistent 128 blocks (1/CU), each owns 8 h-cols = 32 gate rows.
//     W_hh slice bf16 in LDS (64 KB). Per step MFMA [32 x 32gates x K1152],
//     2 N-tiles x 2 M-tiles per wave, K-split over 4 waves, red in LDS.
//     Cross-block h exchange: 8B agent-scope relaxed atomics (LLC-coherent).
//     Barrier: contention-free flag per block (atomic STORE, monotonic t+1,
//     no RMW -- round-4's 16-deep atomicAdd queue removed); wave-0 lanes poll
//     2 flags each + __all ballot. Release order: h-stores -> vmcnt(0) ->
//     flag store -> hs3 history store (off critical path).
//   hs3: [128 regions][16384 rows][2 u64] -- 16B per (batch,step) row,
//     per-block contiguous 256KB. out_gemm A-frag = single 16B load.
//   out_gemm_k: 64x80 tiles (80 = 16 groups of 5 -> lse intra-tile).
// ---------------------------------------------------------------------------

typedef float f4 __attribute__((ext_vector_type(4)));
typedef short s8 __attribute__((ext_vector_type(8)));
typedef unsigned short us8v __attribute__((ext_vector_type(8)));
typedef unsigned short us4v __attribute__((ext_vector_type(4)));
typedef unsigned long long u64;

#define DEV __device__ __forceinline__

DEV unsigned short f2b(float f) {          // fp32 -> bf16 RNE
  unsigned u = __float_as_uint(f);
  return (unsigned short)((u + 0x7FFFu + ((u >> 16) & 1u)) >> 16);
}
DEV float b2f(unsigned short s) { return __uint_as_float(((unsigned)s) << 16); }

DEV f4 MFMA(s8 a, s8 b, f4 c) {
  return __builtin_amdgcn_mfma_f32_16x16x32_bf16(a, b, c, 0, 0, 0);
}
DEV s8 LD8(const unsigned short* p) { return *reinterpret_cast<const s8*>(p); }

DEV s8 LDH(const u64* p) {  // 16B of h via 2 coherent (LLC) 8B atomic loads
  union { u64 q[2]; s8 v; } u;
  u.q[0] = __hip_atomic_load(p, __ATOMIC_RELAXED, __HIP_MEMORY_SCOPE_AGENT);
  u.q[1] = __hip_atomic_load(p + 1, __ATOMIC_RELAXED, __HIP_MEMORY_SCOPE_AGENT);
  return u.v;
}

DEV float sigf(float x) {   // 1/(1+e^-x) via v_exp + v_rcp (~1e-6 rel)
  float e = __builtin_amdgcn_exp2f(x * -1.44269504f);
  return __builtin_amdgcn_rcpf(1.f + e);
}
DEV float tanhf_fast(float x) {  // 1 - 2/(e^{2x}+1); saturates correctly
  float e = __builtin_amdgcn_exp2f(x * 2.88539008f);
  return 1.f - 2.f * __builtin_amdgcn_rcpf(e + 1.f);
}

// ---- workspace layout (bytes) ----
// [0,512)     128 per-block arrival flags (u32, monotonic step count)
// [2048, +131072)   h64: 2 x 32 x 256 u64 (dbl-buffered carry h, bf16 packed)
// [133120, +4MiB)   zt : 512 x 32 x 128 bf16
// [4327424, +3.75MiB) wout16
// [8261632, +32MiB) hs3: 128 regions x 16384 rows x 16B
static constexpr size_t WS_HBUF = 2048;
static constexpr size_t WS_ZT   = 133120;
static constexpr size_t WS_WOUT = 4327424;
static constexpr size_t WS_HS3  = 8261632;
static constexpr size_t WS_END  = 41816064;

// ---------------------------------------------------------------------------
__global__ void cvt_wout_k(const float* __restrict__ W, unsigned short* __restrict__ o) {
  int i = blockIdx.x * 256 + threadIdx.x;         // 491776 float4 units exact
  if (i < 491776) {
    const float4 v = reinterpret_cast<const float4*>(W)[i];
    us4v u; u[0] = f2b(v.x); u[1] = f2b(v.y); u[2] = f2b(v.z); u[3] = f2b(v.w);
    reinterpret_cast<us4v*>(o)[i] = u;
  }
}

__global__ void cvt_z_k(const float* __restrict__ z, unsigned short* __restrict__ zt) {
  int u = blockIdx.x * 256 + threadIdx.x;         // 524288 units exact
  if (u < 524288) {
    int d4 = u & 31, bt = u >> 5;
    int b = bt & 31, t = bt >> 5;
    const float4 v = reinterpret_cast<const float4*>(z)[(b * 512 + t) * 32 + d4];
    us4v uu; uu[0] = f2b(v.x); uu[1] = f2b(v.y); uu[2] = f2b(v.z); uu[3] = f2b(v.w);
    reinterpret_cast<us4v*>(zt)[u] = uu;
  }
}

__global__ void zero_hs_tail_k(u64* __restrict__ hs3u) {
  // rows 16352..16383 (32 rows x 2 u64) of all 128 regions = 8192 u64
  int i = blockIdx.x * 256 + threadIdx.x;
  if (i < 8192) {
    int reg = i >> 6, rr = (i >> 1) & 31, hf = i & 1;
    hs3u[(size_t)reg * 32768 + (size_t)(16352 + rr) * 2 + hf] = 0ull;
  }
}

// ---------------------------------------------------------------------------
// Persistent LSTM. grid=128, block=256 (4 waves). Block blk owns h cols
// [8blk,8blk+8) = 32 gate rows {type*1024 + 8blk + q}. Wave w owns K-slice
// [256w,+256) of W_hh + z-K [32w,+32). 511 steps, flag barrier.
__global__ __launch_bounds__(256, 1) void lstm_k(
    const float* __restrict__ Whh, const float* __restrict__ Wih,
    const float* __restrict__ embed, const float* __restrict__ bih,
    const float* __restrict__ bhh, const int* __restrict__ actions,
    const int* __restrict__ dones, const unsigned short* __restrict__ zt,
    u64* __restrict__ h64, u64* __restrict__ hs3u,
    unsigned* __restrict__ flags) {
  const int blk = blockIdx.x;
  const int tid = threadIdx.x;
  const int lane = tid & 63;
  const int w = tid >> 6;
  const int ln = lane & 15, lk = lane >> 4;

  __shared__ alignas(16) unsigned short whh_sw[32768];   // [kt32][nt2][64][8] 64 KB
  __shared__ alignas(16) unsigned short wz_sw[4096];     // [kz4][nt2][64][8]   8 KB
  __shared__ float abias[18][32];
  __shared__ float red[4][32][34];     // stride 34: write 2-way, read <=4-way
  __shared__ alignas(16) unsigned short st[32][8];   // unmasked h staging
  __shared__ alignas(16) unsigned short stm[32][8];  // masked h staging

  for (int i = tid; i < 32768; i += 256) {
    int j = i & 7, L = (i >> 3) & 63, nt = (i >> 9) & 1, kt = i >> 10;
    int n = nt * 16 + (L & 15);
    int grow = (n >> 3) * 1024 + blk * 8 + (n & 7);
    int k = kt * 32 + ((L >> 4) << 3) + j;
    whh_sw[i] = f2b(Whh[grow * 1024 + k]);
  }
  for (int i = tid; i < 4096; i += 256) {
    int j = i & 7, L = (i >> 3) & 63, nt = (i >> 9) & 1, kz = i >> 10;
    int n = nt * 16 + (L & 15);
    int grow = (n >> 3) * 1024 + blk * 8 + (n & 7);
    int k = kz * 32 + ((L >> 4) << 3) + j;
    wz_sw[i] = f2b(Wih[grow * 144 + k]);
  }
  for (int i = tid; i < 576; i += 256) {
    int a = i >> 5, n = i & 31;
    int grow = (n >> 3) * 1024 + blk * 8 + (n & 7);
    float s = bih[grow] + bhh[grow];
    for (int j = 0; j < 16; ++j) s += embed[a * 16 + j] * Wih[grow * 144 + 128 + j];
    abias[a][n] = s;
  }
  __syncthreads();

  const int eb = tid >> 3, eq = tid & 7;   // epilogue: thread -> (batch, col)
  float c_state = 0.f;

  for (int t = 0; t < 511; ++t) {
    const int p = t & 1;
    const u64* hb = h64 + p * 8192;          // 32 rows x 256 u64

    f4 acc00 = {0.f,0.f,0.f,0.f}, acc01 = {0.f,0.f,0.f,0.f};
    f4 acc10 = {0.f,0.f,0.f,0.f}, acc11 = {0.f,0.f,0.f,0.f};

    {  // z contribution: independent of h -> overlaps barrier wait
      const unsigned short* zb = zt + (size_t)t * 4096;
      const int kz = w * 32 + (lk << 3);
      s8 a0 = LD8(zb + ln * 128 + kz);
      s8 a1 = LD8(zb + (ln + 16) * 128 + kz);
      s8 b0 = LD8(wz_sw + (((w << 1) + 0) * 64 + lane) * 8);
      s8 b1 = LD8(wz_sw + (((w << 1) + 1) * 64 + lane) * 8);
      acc00 = MFMA(a0, b0, acc00);  acc01 = MFMA(a0, b1, acc01);
      acc10 = MFMA(a1, b0, acc10);  acc11 = MFMA(a1, b1, acc11);
    }
    // per-step scalars: independent of h, issue before the spin
    const int a_t = actions[eb * 512 + t];
    const float m_t = 1.f - (float)dones[eb * 512 + t];

    if (t) {  // wait for step t-1: all 128 flags >= t. Wave 0 lanes poll 2 each.
      if (w == 0) {
        const unsigned tgt = (unsigned)t;
        for (unsigned spin = 0; spin < (1u << 20); ++spin) {
          unsigned f0 = __hip_atomic_load(flags + lane, __ATOMIC_RELAXED,
                                          __HIP_MEMORY_SCOPE_AGENT);
          unsigned f1 = __hip_atomic_load(flags + 64 + lane, __ATOMIC_RELAXED,
                                          __HIP_MEMORY_SCOPE_AGENT);
          if (__all(f0 >= tgt && f1 >= tgt)) break;
          __builtin_amdgcn_s_sleep(1);
        }
      }
      __syncthreads();
    }

#pragma unroll
    for (int kk = 0; kk < 8; ++kk) {   // this wave's 8 K-steps of W_hh
      const int kt = w * 8 + kk;
      s8 a0 = LDH(hb + ln * 256 + kt * 8 + (lk << 1));
      s8 a1 = LDH(hb + (ln + 16) * 256 + kt * 8 + (lk << 1));
      s8 b0 = LD8(whh_sw + (((kt << 1) + 0) * 64 + lane) * 8);
      s8 b1 = LD8(whh_sw + (((kt << 1) + 1) * 64 + lane) * 8);
      acc00 = MFMA(a0, b0, acc00);  acc01 = MFMA(a0, b1, acc01);
      acc10 = MFMA(a1, b0, acc10);  acc11 = MFMA(a1, b1, acc11);
    }

    // D layout: row(batch) = 16*mt + 4*lk + j, col(gate) = 16*nt + ln
#pragma unroll
    for (int j = 0; j < 4; ++j) {
      red[w][(lk << 2) + j][ln]           = acc00[j];
      red[w][(lk << 2) + j][16 + ln]      = acc01[j];
      red[w][16 + (lk << 2) + j][ln]      = acc10[j];
      red[w][16 + (lk << 2) + j][16 + ln] = acc11[j];
    }
    __syncthreads();

    {  // epilogue: all 256 threads, one per (batch eb, col eq)
      float gi = 0.f, gf = 0.f, gg = 0.f, go = 0.f;
#pragma unroll
      for (int ww = 0; ww < 4; ++ww) {
        gi += red[ww][eb][eq];
        gf += red[ww][eb][8 + eq];
        gg += red[ww][eb][16 + eq];
        go += red[ww][eb][24 + eq];
      }
      gi += abias[a_t][eq];       gf += abias[a_t][8 + eq];
      gg += abias[a_t][16 + eq];  go += abias[a_t][24 + eq];
      const float si = sigf(gi), sf = sigf(gf), so = sigf(go);
      const float cn = sf * c_state + si * tanhf_fast(gg);
      const float hn = so * tanhf_fast(cn);
      c_state = cn * m_t;                      // fp32 carry
      st[eb][eq]  = f2b(hn);                   // unmasked -> hs3
      stm[eb][eq] = f2b(hn * m_t);             // masked   -> carry h
    }
    __syncthreads();

    if (tid < 64) {  // carry h: 64 lanes x 8B agent atomics (one instr)
      const int bb = tid >> 1, hf = tid & 1;
      const u64 vm = reinterpret_cast<const u64*>(&stm[bb][0])[hf];
      __hip_atomic_store(h64 + (1 - p) * 8192 + bb * 256 + blk * 2 + hf, vm,
                         __ATOMIC_RELAXED, __HIP_MEMORY_SCOPE_AGENT);
      asm volatile("s_waitcnt vmcnt(0)" ::: "memory");  // drain before flag
    }
    if (tid == 0)
      __hip_atomic_store(flags + blk, (unsigned)(t + 1),
                         __ATOMIC_RELAXED, __HIP_MEMORY_SCOPE_AGENT);
    if (tid < 32) {  // history (off critical path): 16B per batch
      us8v v = *reinterpret_cast<const us8v*>(&st[tid][0]);
      *reinterpret_cast<us8v*>(hs3u + (size_t)blk * 32768 +
                               (size_t)(tid * 511 + t) * 2) = v;
    }
  }
}

// ---------------------------------------------------------------------------
// out = hs @ W_out^T (+bias), fused logsumexp on the logmix third.
// grid = (256 Mblk of 64 rows, 24 Nblk of 80 cols). Wave w -> rows [w*16,+16).
__global__ __launch_bounds__(256, 2) void out_gemm_k(
    const u64* __restrict__ hs3u, const unsigned short* __restrict__ wout,
    const float* __restrict__ b_out, float* __restrict__ out) {
  const int mblk = blockIdx.x, nblk = blockIdx.y;
  const int tid = threadIdx.x, lane = tid & 63, w = tid >> 6;
  const int ln = lane & 15, lk = lane >> 4;
  __shared__ alignas(16) unsigned char smraw[21760];
  unsigned short* bsm = (unsigned short*)smraw;  // [80][136] bf16 B-chunk
  float* ep = (float*)smraw;                     // [64][84] f32 epilogue tile

  const int r0 = mblk * 64 + w * 16;
  f4 acc[5];
#pragma unroll
  for (int s = 0; s < 5; ++s) acc[s] = (f4){0.f, 0.f, 0.f, 0.f};

  for (int kc = 0; kc < 8; ++kc) {  // K chunks of 128
#pragma unroll
    for (int ii = 0; ii < 5; ++ii) {           // 1280 us8 chunks exact
      int i = tid + ii * 256;
      int n = i >> 4, k16 = i & 15;
      us8v v = *reinterpret_cast<const us8v*>(
          wout + (size_t)(nblk * 80 + n) * 1024 + kc * 128 + (k16 << 3));
      *reinterpret_cast<us8v*>(bsm + n * 136 + (k16 << 3)) = v;
    }
    __syncthreads();
#pragma unroll
    for (int ks = 0; ks < 4; ++ks) {
      const int k0 = kc * 128 + ks * 32 + (lk << 3);
      s8 a = *reinterpret_cast<const s8*>(
          hs3u + (size_t)(k0 >> 3) * 32768 + (size_t)(r0 + ln) * 2);
#pragma unroll
      for (int s = 0; s < 5; ++s) {
        s8 b = LD8(bsm + (s * 16 + ln) * 136 + ks * 32 + (lk << 3));
        acc[s] = MFMA(a, b, acc[s]);
      }
    }
    __syncthreads();
  }

  const int T = nblk >> 3;  // 0 logmix, 1 mu, 2 logstd
  if (T) {
    float* base = out + (size_t)10465280 * T;
    const int lc0 = (nblk - (T << 3)) * 80;
#pragma unroll
    for (int s = 0; s < 5; ++s) {
      const int lc = lc0 + s * 16 + ln;
      const float bias = b_out[T * 640 + lc];
#pragma unroll
      for (int j = 0; j < 4; ++j) {
        const int row = r0 + (lk << 2) + j;
        if (row < 16352) base[(size_t)row * 640 + lc] = acc[s][j] + bias;
      }
    }
  } else {  // logmix: bounce through LDS, per-(row, z-group) logsumexp over 5
#pragma unroll
    for (int s = 0; s < 5; ++s) {
      const float bias = b_out[nblk * 80 + s * 16 + ln];
#pragma unroll
      for (int j = 0; j < 4; ++j)
        ep[(w * 16 + (lk << 2) + j) * 84 + s * 16 + ln] = acc[s][j] + bias;
    }
    __syncthreads();
    for (int task = tid; task < 1024; task += 256) {
      const int rr = task >> 4, grp = task & 15;
      const int row = mblk * 64 + rr;
      const float* e = ep + rr * 84 + grp * 5;
      float v0 = e[0], v1 = e[1], v2 = e[2], v3 = e[3], v4 = e[4];
      float mx = fmaxf(fmaxf(fmaxf(v0, v1), fmaxf(v2, v3)), v4);
      float ssum = expf(v0 - mx) + expf(v1 - mx) + expf(v2 - mx) +
                   expf(v3 - mx) + expf(v4 - mx);
      float lse = mx + logf(ssum);
      if (row < 16352) {
        float* o = out + (size_t)row * 640 + nblk * 80 + grp * 5;
        o[0] = v0 - lse; o[1] = v1 - lse; o[2] = v2 - lse;
        o[3] = v3 - lse; o[4] = v4 - lse;
      }
    }
  }
}

// ---------------------------------------------------------------------------
__global__ __launch_bounds__(256) void donep_k(
    const u64* __restrict__ hs3u, const unsigned short* __restrict__ wout,
    const float* __restrict__ b_out, float* __restrict__ out) {
  const int lane = threadIdx.x & 63;
  const int wv = (blockIdx.x * 256 + threadIdx.x) >> 6;  // 2048 waves
  const unsigned short* wrow = wout + (size_t)1920 * 1024 + lane * 16;
  float wl[16];
#pragma unroll
  for (int i = 0; i < 16; ++i) wl[i] = b2f(wrow[i]);
  const float bias = b_out[1920];
  for (int r = wv; r < 16352; r += 2048) {
    float d = 0.f;
#pragma unroll
    for (int j = 0; j < 2; ++j) {   // regions 2*lane+j -> cols lane*16+8j..+8
      union { u64 q2[2]; unsigned short h[8]; } u;
      const u64* pp = hs3u + (size_t)(lane * 2 + j) * 32768 + (size_t)r * 2;
      u.q2[0] = pp[0]; u.q2[1] = pp[1];
#pragma unroll
      for (int i = 0; i < 8; ++i) d += b2f(u.h[i]) * wl[j * 8 + i];
    }
#pragma unroll
    for (int off = 32; off; off >>= 1) d += __shfl_down(d, off, 64);
    if (lane == 0) out[31395840 + r] = d + bias;
  }
}

// ---------------------------------------------------------------------------
extern "C" void kernel_launch(void* const* d_in, const int* in_sizes, int n_in,
                              void* d_out, int out_size, void* d_ws, size_t ws_size,
                              hipStream_t stream) {
  const float* z       = (const float*)d_in[0];
  const int*   actions = (const int*)d_in[1];
  const int*   dones   = (const int*)d_in[2];
  const float* embed   = (const float*)d_in[3];
  const float* Wih     = (const float*)d_in[4];
  const float* Whh     = (const float*)d_in[5];
  const float* bih     = (const float*)d_in[6];
  const float* bhh     = (const float*)d_in[7];
  const float* Wout    = (const float*)d_in[8];
  const float* bout    = (const float*)d_in[9];
  float* out = (float*)d_out;

  if (ws_size < WS_END) return;  // fail visibly rather than corrupt memory

  char* ws = (char*)d_ws;
  unsigned* flags        = (unsigned*)(ws);
  u64* h64               = (u64*)(ws + WS_HBUF);
  unsigned short* zt     = (unsigned short*)(ws + WS_ZT);
  unsigned short* wout16 = (unsigned short*)(ws + WS_WOUT);
  u64* hs3u              = (u64*)(ws + WS_HS3);

  // zero flags + initial h (h0 = 0); must happen every launch
  hipMemsetAsync(d_ws, 0, 133120, stream);

  cvt_wout_k<<<1921, 256, 0, stream>>>(Wout, wout16);
  cvt_z_k<<<2048, 256, 0, stream>>>(z, zt);
  zero_hs_tail_k<<<32, 256, 0, stream>>>(hs3u);
  lstm_k<<<128, 256, 0, stream>>>(Whh, Wih, embed, bih, bhh, actions, dones,
                                  zt, h64, hs3u, flags);
  out_gemm_k<<<dim3(256, 24), 256, 0, stream>>>(hs3u, wout16, bout, out);
  donep_k<<<512, 256, 0, stream>>>(hs3u, wout16, bout, out);
}